// Round 8
// baseline (616.728 us; speedup 1.0000x reference)
//
#include <hip/hip_runtime.h>
#include <math.h>

#define Bsz 256
#define T   512
#define Dd  8
#define Hh  120
#define Ll  4
#define NHn 8
#define HDd 15
#define HP  20      // padded head row stride (bank-spread, 16B-aligned: 80B)
#define EPSf 1e-5f

__device__ __forceinline__ float fast_rcp(float x) {
#if __has_builtin(__builtin_amdgcn_rcpf)
    return __builtin_amdgcn_rcpf(x);
#else
    return 1.f / x;
#endif
}
__device__ __forceinline__ float tanh_fast(float x) {
    float e = __expf(2.f * x);
    return 1.f - 2.f * fast_rcp(e + 1.f);
}
__device__ __forceinline__ float sigm_fast(float x) {
    return fast_rcp(1.f + __expf(-x));
}

#define LD16(dst, srcp) { \
    const float4* _h4 = (const float4*)(srcp); \
    const float4 _a=_h4[0], _b=_h4[1], _c=_h4[2], _d=_h4[3]; \
    dst[0]=_a.x; dst[1]=_a.y; dst[2]=_a.z; dst[3]=_a.w; \
    dst[4]=_b.x; dst[5]=_b.y; dst[6]=_b.z; dst[7]=_b.w; \
    dst[8]=_c.x; dst[9]=_c.y; dst[10]=_c.z; dst[11]=_c.w; \
    dst[12]=_d.x; dst[13]=_d.y; dst[14]=_d.z; dst[15]=_d.w; }

// One sLSTM unit update for one lane: 4 gates (i,f,z,o), exp-gated state.
// All indices compile-time after inlining -> everything stays in registers.
__device__ __forceinline__ float unit_step(
    const float xv[8], const float hv[16],
    const float w[4][8], const float r[4][15], const float bsc[4],
    float& c, float& nn, float& m)
{
    float gi = bsc[0], gf = bsc[1], gz = bsc[2], go = bsc[3];
#pragma unroll
    for (int d = 0; d < 8; ++d) {
        gi = fmaf(xv[d], w[0][d], gi);
        gf = fmaf(xv[d], w[1][d], gf);
        gz = fmaf(xv[d], w[2][d], gz);
        go = fmaf(xv[d], w[3][d], go);
    }
#pragma unroll
    for (int k = 0; k < 15; ++k) {
        gi = fmaf(hv[k], r[0][k], gi);
        gf = fmaf(hv[k], r[1][k], gf);
        gz = fmaf(hv[k], r[2][k], gz);
        go = fmaf(hv[k], r[3][k], go);
    }
    const float z  = tanh_fast(gz);
    const float o  = sigm_fast(go);
    const float mn = fmaxf(gf + m, gi);
    const float ip = __expf(gi - mn);
    const float fp = __expf(gf + m - mn);
    c  = fmaf(fp, c, ip * z);
    nn = fmaf(fp, nn, ip);
    m  = mn;
    return o * c * fast_rcp(nn);
}

// Block = 256 threads = 4 waves; wave w = layer w (ONE wave per SIMD).
// waves_per_eu(1,1): RA budget ~512 regs/wave -> 192 weight floats/lane stay
// register-resident (impossible at 2 waves/SIMD, the R3-R7 wall).
// Lane u<60 handles units 2u, 2u+1. h-buffers are WAVE-PRIVATE (no barrier
// needed for the recurrence; compiler inserts lgkmcnt for write->read).
// Skew: wave l does gates(t_g = tau-2l) then projection(t_p = t_g-1) in the
// same tick; xs handoff to wave l+1 is protected by ONE barrier per tick.
__global__
__attribute__((amdgpu_flat_work_group_size(256, 256)))
__attribute__((amdgpu_waves_per_eu(1, 1)))
void slstm_kernel(
    const float* __restrict__ x,
    const float* __restrict__ Wi, const float* __restrict__ Wf,
    const float* __restrict__ Wz, const float* __restrict__ Wo,
    const float* __restrict__ Ri, const float* __restrict__ Rf,
    const float* __restrict__ Rz, const float* __restrict__ Ro,
    const float* __restrict__ bi, const float* __restrict__ bf,
    const float* __restrict__ bz, const float* __restrict__ bo,
    const float* __restrict__ Wp, const float* __restrict__ bp,
    float* __restrict__ last_out)   // [Bsz][Dd]
{
    __shared__ __align__(16) float xs[T * Dd];             // 16 KB residual stream
    __shared__ __align__(16) float hb[Ll][2][NHn * HP];    // wave-private h, padded
    __shared__ __align__(16) float wp_s[Ll][Dd][NHn][16];  // Wp rows, pad[15]=0

    const int tid  = threadIdx.x;
    const int b    = blockIdx.x;
    const int l    = tid >> 6;    // layer = wave
    const int lane = tid & 63;

    // ---- prologue: stage x, zero h, stage Wp ----
    {
        const float4* xg = (const float4*)(x + (size_t)b * T * Dd);
        float4* xs4 = (float4*)xs;
#pragma unroll
        for (int i = 0; i < 4; ++i) xs4[tid + 256 * i] = xg[tid + 256 * i];
        float* hbf = (float*)hb;                  // Ll*2*NHn*HP = 1280 floats
#pragma unroll
        for (int i = 0; i < 5; ++i) hbf[tid + 256 * i] = 0.f;
        // wp_s: [l][d][ch][k] = Wp[l, d, ch*15+k] (k<15), 0 for k=15
        for (int i = tid; i < Ll * Dd * NHn * 16; i += 256) {
            const int k  = i & 15;
            const int ch = (i >> 4) & 7;
            const int d  = (i >> 7) & 7;
            const int ll = i >> 10;
            ((float*)wp_s)[i] = (k < 15) ? Wp[ll * Dd * Hh + d * Hh + ch * HDd + k] : 0.f;
        }
    }

    // ---- per-lane weights for 2 units -> registers (192 floats) ----
    const bool act = (lane < 60);
    const int u0 = act ? 2 * lane     : 0;
    const int u1 = act ? 2 * lane + 1 : 1;
    const int n0 = u0 / HDd, e0 = u0 - HDd * n0;
    const int n1 = u1 / HDd, e1 = u1 - HDd * n1;

    const float* Wg[4] = {Wi, Wf, Wz, Wo};
    const float* Rg[4] = {Ri, Rf, Rz, Ro};
    const float* bg[4] = {bi, bf, bz, bo};

    float ww0[4][8], ww1[4][8], rr0[4][15], rr1[4][15], bb0[4], bb1[4];
#pragma unroll
    for (int g = 0; g < 4; ++g) {
        const int row0 = (l * Hh + u0) * Dd, row1 = (l * Hh + u1) * Dd;
#pragma unroll
        for (int d = 0; d < 8; ++d) { ww0[g][d] = Wg[g][row0 + d]; ww1[g][d] = Wg[g][row1 + d]; }
        const int rb0 = ((l * NHn + n0) * HDd) * HDd + e0;
        const int rb1 = ((l * NHn + n1) * HDd) * HDd + e1;
#pragma unroll
        for (int k = 0; k < 15; ++k) { rr0[g][k] = Rg[g][rb0 + k * HDd]; rr1[g][k] = Rg[g][rb1 + k * HDd]; }
        bb0[g] = bg[g][l * Hh + u0]; bb1[g] = bg[g][l * Hh + u1];
    }

    const int ch = lane >> 3, d8 = lane & 7;
    const float bp_r = bp[l * Dd + d8];

    float c0 = 0.f, ns0 = 0.f, m0 = 0.f;
    float c1 = 0.f, ns1 = 0.f, m1 = 0.f;

    __syncthreads();

    // ---- pipelined recurrence: ONE 4-wave barrier per tick ----
    for (int tau = 0; tau < T + 2 * Ll - 1; ++tau) {
        const int t_g = tau - 2 * l;
        const int t_p = t_g - 1;

        if (act && (t_g >= 0) && (t_g < T)) {
            float xv[8];
            {
                const float4* xt4 = (const float4*)(xs + t_g * Dd);
                const float4 xa = xt4[0], xb2 = xt4[1];
                xv[0]=xa.x; xv[1]=xa.y; xv[2]=xa.z; xv[3]=xa.w;
                xv[4]=xb2.x; xv[5]=xb2.y; xv[6]=xb2.z; xv[7]=xb2.w;
            }
            const float* hbase = hb[l][t_g & 1];
            float hv0[16], hv1[16];
            LD16(hv0, hbase + n0 * HP);
            LD16(hv1, hbase + n1 * HP);
            const float h0n = unit_step(xv, hv0, ww0, rr0, bb0, c0, ns0, m0);
            const float h1n = unit_step(xv, hv1, ww1, rr1, bb1, c1, ns1, m1);
            float* hw = hb[l][(t_g & 1) ^ 1];
            hw[n0 * HP + e0] = h0n;
            hw[n1 * HP + e1] = h1n;
        }

        // projection of h(t_p): all 64 lanes; lane (ch,d8) dots head-ch row
        if ((t_p >= 0) && (t_p < T)) {
            float hr[16], wr[16];
            LD16(hr, hb[l][t_g & 1] + ch * HP);   // h(t_p) buffer == (t_g&1)
            LD16(wr, &wp_s[l][d8][ch][0]);
            float s = 0.f;
#pragma unroll
            for (int k = 0; k < 15; ++k) s = fmaf(hr[k], wr[k], s);
            s += __shfl_xor(s, 8);
            s += __shfl_xor(s, 16);
            s += __shfl_xor(s, 32);
            if (lane < Dd) xs[t_p * Dd + lane] += s + bp_r;
        }

        __syncthreads();
    }

    if (tid < Dd) last_out[b * Dd + tid] = xs[(T - 1) * Dd + tid];
}

// One block of Bsz threads: batch-norm over batch + FC + sigmoid.
__global__ __launch_bounds__(Bsz) void bn_fc_kernel(
    const float* __restrict__ last,   // [Bsz][Dd]
    const float* __restrict__ gamma, const float* __restrict__ beta,
    const float* __restrict__ Wfc,   const float* __restrict__ bfc,
    float* __restrict__ out)          // [Bsz]
{
    __shared__ __align__(16) float ls[Bsz][Dd];
    __shared__ float rsum[32][Dd], rsq[32][Dd];
    __shared__ float mu[Dd], rstdg[Dd], bet[Dd], wfc[Dd];
    const int tid = threadIdx.x;
    {
        const float4* lg = (const float4*)last;
        ((float4*)ls)[tid]       = lg[tid];
        ((float4*)ls)[tid + 256] = lg[tid + 256];
    }
    __syncthreads();
    {
        const int d = tid & 7, g = tid >> 3;
        float s = 0.f, q = 0.f;
#pragma unroll
        for (int k = 0; k < 8; ++k) {
            const float v = ls[g + 32 * k][d];
            s += v; q = fmaf(v, v, q);
        }
        rsum[g][d] = s; rsq[g][d] = q;
    }
    __syncthreads();
    if (tid < Dd) {
        float s = 0.f, q = 0.f;
#pragma unroll
        for (int g = 0; g < 32; ++g) { s += rsum[g][tid]; q += rsq[g][tid]; }
        const float mean = s * (1.f / Bsz);
        const float var  = q * (1.f / Bsz) - mean * mean;
        mu[tid]    = mean;
        rstdg[tid] = rsqrtf(fmaxf(var, 0.f) + EPSf) * gamma[tid];
        bet[tid]   = beta[tid];
        wfc[tid]   = Wfc[tid];
    }
    __syncthreads();
    float acc = bfc[0];
#pragma unroll
    for (int d = 0; d < Dd; ++d)
        acc += ((ls[tid][d] - mu[d]) * rstdg[d] + bet[d]) * wfc[d];
    out[tid] = sigm_fast(acc);
}

extern "C" void kernel_launch(void* const* d_in, const int* in_sizes, int n_in,
                              void* d_out, int out_size, void* d_ws, size_t ws_size,
                              hipStream_t stream) {
    const float* x    = (const float*)d_in[0];
    const float* Wi   = (const float*)d_in[1];
    const float* Wf   = (const float*)d_in[2];
    const float* Wz   = (const float*)d_in[3];
    const float* Wo   = (const float*)d_in[4];
    const float* Ri   = (const float*)d_in[5];
    const float* Rf   = (const float*)d_in[6];
    const float* Rz   = (const float*)d_in[7];
    const float* Ro   = (const float*)d_in[8];
    const float* bi   = (const float*)d_in[9];
    const float* bf   = (const float*)d_in[10];
    const float* bz   = (const float*)d_in[11];
    const float* bo   = (const float*)d_in[12];
    const float* Wp   = (const float*)d_in[13];
    const float* bp   = (const float*)d_in[14];
    const float* gamma= (const float*)d_in[15];
    const float* beta = (const float*)d_in[16];
    const float* Wfc  = (const float*)d_in[17];
    const float* bfc  = (const float*)d_in[18];

    float* last_ws = (float*)d_ws;          // Bsz*Dd floats
    float* out     = (float*)d_out;         // Bsz floats

    slstm_kernel<<<Bsz, 256, 0, stream>>>(x, Wi, Wf, Wz, Wo, Ri, Rf, Rz, Ro,
                                          bi, bf, bz, bo, Wp, bp, last_ws);
    bn_fc_kernel<<<1, Bsz, 0, stream>>>(last_ws, gamma, beta, Wfc, bfc, out);
}